// Round 4
// baseline (1597.496 us; speedup 1.0000x reference)
//
#include <hip/hip_runtime.h>
#include <hip/hip_bf16.h>
#include <stdint.h>

// Problem constants
#define NRES 8192
#define KNB  15
#define SDIM 128
#define EDIM 24
#define HIDD 512
#define NH   8
#define QDIM 256   // H*A
#define MIXN 10

struct F3 { float x, y, z; };
__device__ __forceinline__ F3 f3sub(F3 a, F3 b) { return {a.x-b.x, a.y-b.y, a.z-b.z}; }
__device__ __forceinline__ F3 f3cross(F3 a, F3 b) {
  return {a.y*b.z - a.z*b.y, a.z*b.x - a.x*b.z, a.x*b.y - a.y*b.x};
}
__device__ __forceinline__ F3 f3norm(F3 a) {
  float l = sqrtf(a.x*a.x + a.y*a.y + a.z*a.z) + 1e-8f;
  float r = 1.f / l;
  return {a.x*r, a.y*r, a.z*r};
}
__device__ __forceinline__ F3 ldpos(const float* p, int i) { return {p[i*3], p[i*3+1], p[i*3+2]}; }

// ---------------- geometry ----------------
__global__ void pos_kernel(const float* __restrict__ tert, float* __restrict__ pos) {
  int n = blockIdx.x * blockDim.x + threadIdx.x;
  if (n >= NRES) return;
  pos[n*3+0] = tert[n*9+3];
  pos[n*3+1] = tert[n*9+4];
  pos[n*3+2] = tert[n*9+5];
}

__global__ void frames_kernel(const float* __restrict__ pos, float* __restrict__ R) {
  int m = blockIdx.x * blockDim.x + threadIdx.x;
  if (m >= NRES) return;
  int s = m - 1; if (s < 0) s = 0; if (s > NRES-3) s = NRES-3;
  F3 p0 = ldpos(pos, s), p1 = ldpos(pos, s+1), p2 = ldpos(pos, s+2);
  F3 u0 = f3norm(f3sub(p1, p0));
  F3 u1 = f3norm(f3sub(p2, p1));
  F3 b  = f3norm(f3sub(u0, u1));
  F3 nn = f3norm(f3cross(u0, u1));
  F3 o  = f3cross(b, nn);
  float* r = R + m*9;
  r[0]=b.x; r[1]=nn.x; r[2]=o.x;
  r[3]=b.y; r[4]=nn.y; r[5]=o.y;
  r[6]=b.z; r[7]=nn.z; r[8]=o.z;
}

__device__ __forceinline__ float quat_comp(float t, float a, float b) {
  float s = (a > b) ? 1.f : ((a < b) ? -1.f : 0.f);
  return 0.5f * sqrtf(fmaxf(1e-8f, t)) * s;
}

__global__ void edges_kernel(const float* __restrict__ pos, const float* __restrict__ R,
                             const int* __restrict__ structure, float* __restrict__ edges) {
  int id = blockIdx.x * blockDim.x + threadIdx.x;
  if (id >= NRES*KNB) return;
  int n = id / KNB;
  int tprev = (n - 1) & (NRES - 1);
  int sidx = structure[id];
  F3 pt = ldpos(pos, tprev), ps = ldpos(pos, sidx);
  F3 dv = f3sub(ps, pt);
  float dist = sqrtf(dv.x*dv.x + dv.y*dv.y + dv.z*dv.z);
  float rinv = 1.f / (dist + 1e-8f);
  F3 dh = {dv.x*rinv, dv.y*rinv, dv.z*rinv};
  float Rt[9], Rs[9];
#pragma unroll
  for (int i = 0; i < 9; i++) { Rt[i] = R[tprev*9+i]; Rs[i] = R[sidx*9+i]; }
  float dir[3];
#pragma unroll
  for (int i = 0; i < 3; i++) dir[i] = Rt[i]*dh.x + Rt[3+i]*dh.y + Rt[6+i]*dh.z;
  float Rr[9];
#pragma unroll
  for (int i = 0; i < 3; i++)
#pragma unroll
    for (int l = 0; l < 3; l++)
      Rr[i*3+l] = Rt[i]*Rs[l] + Rt[3+i]*Rs[3+l] + Rt[6+i]*Rs[6+l];
  float m00 = Rr[0], m11 = Rr[4], m22 = Rr[8];
  float qw = 0.5f * sqrtf(fmaxf(1e-8f, 1.f + m00 + m11 + m22));
  float qx = quat_comp(1.f + m00 - m11 - m22, Rr[7], Rr[5]);
  float qy = quat_comp(1.f - m00 + m11 - m22, Rr[2], Rr[6]);
  float qz = quat_comp(1.f - m00 - m11 + m22, Rr[3], Rr[1]);
  float* e = edges + (size_t)id * EDIM;
#pragma unroll
  for (int j = 0; j < 16; j++) {
    float mu = (20.f / 15.f) * j;            // linspace(0,20,16)
    float zz = (dist - mu) * (1.f / 1.25f);  // sigma = 20/16
    e[j] = expf(-zz*zz);
  }
  e[16] = dir[0]; e[17] = dir[1]; e[18] = dir[2];
  e[19] = qw; e[20] = qx; e[21] = qy; e[22] = qz;
  e[23] = (float)(sidx - tprev) * 0.01f;
}

// ---------------- input embedding ----------------
__global__ __launch_bounds__(128) void init_kernel(const float* __restrict__ angles,
    const float* __restrict__ W_in, const float* __restrict__ b_in,
    const float* __restrict__ W_pre, const float* __restrict__ b_pre, float* __restrict__ x) {
  int n = blockIdx.x, c = threadIdx.x;
  __shared__ float fs[128];
  float af[6];
  if (n == 0) { af[0]=af[1]=af[2]=0.f; af[3]=af[4]=af[5]=1.f; }
  else {
#pragma unroll
    for (int j = 0; j < 3; j++) {
      float p = angles[(n-1)*3 + j];
      af[j] = sinf(p); af[3+j] = cosf(p);
    }
  }
  float f = b_in[c];
#pragma unroll
  for (int j = 0; j < 6; j++) f += af[j] * W_in[j*SDIM + c];
  fs[c] = f;
  __syncthreads();
  float xv = b_pre[c];
  for (int j = 0; j < 128; j++) xv += fs[j] * W_pre[j*SDIM + c];
  x[(size_t)n*SDIM + c] = xv;
}

// ---------------- layernorm: f32 -> f32 ----------------
__global__ __launch_bounds__(128) void ln_kernel(const float* __restrict__ x,
    const float* __restrict__ g, const float* __restrict__ b, float* __restrict__ out) {
  int n = blockIdx.x, c = threadIdx.x;
  float v = x[(size_t)n*SDIM + c];
  float s = v;
#pragma unroll
  for (int m = 32; m >= 1; m >>= 1) s += __shfl_xor(s, m, 64);
  __shared__ float p1[2], p2[2];
  if ((c & 63) == 0) p1[c >> 6] = s;
  __syncthreads();
  float mean = (p1[0] + p1[1]) * (1.f/128.f);
  float d = v - mean;
  float s2 = d * d;
#pragma unroll
  for (int m = 32; m >= 1; m >>= 1) s2 += __shfl_xor(s2, m, 64);
  if ((c & 63) == 0) p2[c >> 6] = s2;
  __syncthreads();
  float var = (p2[0] + p2[1]) * (1.f/128.f);
  out[(size_t)n*SDIM + c] = d * rsqrtf(var + 1e-5f) * g[c] + b[c];
}

// ---------------- tiled SGEMM: C(MxN) = A(MxK,f32) @ B(KxN,f32), f32 acc ----------------
// MODE 0: C = AB + bias ; MODE 1: C = relu(AB + bias) ; MODE 2: C += AB + bias
// Requires M%64==0, N%64==0, K%16==0.
template<int MODE>
__global__ __launch_bounds__(256) void gemm_kernel(const float* __restrict__ A, const float* __restrict__ B,
    const float* __restrict__ bias, float* __restrict__ C, int M, int Kd, int Nd) {
  __shared__ float As[16][68];
  __shared__ float Bs[16][68];
  int t = threadIdx.x;
  int m0 = blockIdx.y * 64, n0 = blockIdx.x * 64;
  int tx = t & 15, ty = t >> 4;
  int am = t >> 2, ak = (t & 3) * 4;   // A stage: 64 rows x 16 k, 4 f32 each
  int bk = t >> 4, bn = (t & 15) * 4;  // B stage: 16 k x 64 cols, 4 f32 each
  float acc[4][4] = {};
  for (int k0 = 0; k0 < Kd; k0 += 16) {
    float4 araw = *(const float4*)(A + (size_t)(m0 + am)*Kd + k0 + ak);
    float4 braw = *(const float4*)(B + (size_t)(k0 + bk)*Nd + n0 + bn);
    __syncthreads();
    As[ak+0][am] = araw.x; As[ak+1][am] = araw.y; As[ak+2][am] = araw.z; As[ak+3][am] = araw.w;
    Bs[bk][bn+0] = braw.x; Bs[bk][bn+1] = braw.y; Bs[bk][bn+2] = braw.z; Bs[bk][bn+3] = braw.w;
    __syncthreads();
#pragma unroll
    for (int k = 0; k < 16; ++k) {
      float4 a = *(const float4*)&As[k][ty*4];
      float4 b = *(const float4*)&Bs[k][tx*4];
      acc[0][0] += a.x*b.x; acc[0][1] += a.x*b.y; acc[0][2] += a.x*b.z; acc[0][3] += a.x*b.w;
      acc[1][0] += a.y*b.x; acc[1][1] += a.y*b.y; acc[1][2] += a.y*b.z; acc[1][3] += a.y*b.w;
      acc[2][0] += a.z*b.x; acc[2][1] += a.z*b.y; acc[2][2] += a.z*b.z; acc[2][3] += a.z*b.w;
      acc[3][0] += a.w*b.x; acc[3][1] += a.w*b.y; acc[3][2] += a.w*b.z; acc[3][3] += a.w*b.w;
    }
  }
  int mb = m0 + ty*4, nb = n0 + tx*4;
  float bj[4];
#pragma unroll
  for (int j = 0; j < 4; j++) bj[j] = bias ? bias[nb + j] : 0.f;
#pragma unroll
  for (int i = 0; i < 4; i++) {
    float* crow = C + (size_t)(mb + i)*Nd + nb;
#pragma unroll
    for (int j = 0; j < 4; j++) {
      float v = acc[i][j] + bj[j];
      if (MODE == 1) v = fmaxf(v, 0.f);
      if (MODE == 2) crow[j] += v; else crow[j] = v;
    }
  }
}

// ---------------- fused attention (one block = one node, 256 threads = 256 channels) ----------------
__global__ __launch_bounds__(256) void attn_kernel(const float* __restrict__ q,
    const float* __restrict__ pk, const float* __restrict__ pv,
    const float* __restrict__ edges, const int* __restrict__ structure,
    const float* __restrict__ WkB, const float* __restrict__ bk,
    const float* __restrict__ WvB, const float* __restrict__ bv,
    const float* __restrict__ Wo, const float* __restrict__ bo, float* __restrict__ x) {
  int n = blockIdx.x, c = threadIdx.x;
  __shared__ float e_s[KNB*EDIM];
  __shared__ int   si[KNB];
  __shared__ float logit_s[KNB][NH];
  __shared__ float attw_s[KNB][NH];
  __shared__ float att_s[256];
  __shared__ float part_s[2][128];
  for (int i = c; i < KNB*EDIM; i += 256) e_s[i] = edges[(size_t)n*KNB*EDIM + i];
  if (c < KNB) si[c] = structure[n*KNB + c];
  float wkb[EDIM], wvb[EDIM];
#pragma unroll
  for (int j = 0; j < EDIM; j++) { wkb[j] = WkB[j*QDIM + c]; wvb[j] = WvB[j*QDIM + c]; }
  float bkc = bk[c], bvc = bv[c];
  float qc = q[(size_t)n*QDIM + c];
  __syncthreads();
  float kcs[KNB], vcs[KNB];
#pragma unroll
  for (int kk = 0; kk < KNB; kk++) {
    int s = si[kk];
    float kc = pk[(size_t)s*QDIM + c] + bkc;
    float vc = pv[(size_t)s*QDIM + c] + bvc;
#pragma unroll
    for (int j = 0; j < EDIM; j++) {
      float e = e_s[kk*EDIM + j];
      kc += e * wkb[j];
      vc += e * wvb[j];
    }
    kcs[kk] = kc; vcs[kk] = vc;
  }
  int h = c >> 5;
#pragma unroll
  for (int kk = 0; kk < KNB; kk++) {
    float p = qc * kcs[kk];
    p += __shfl_xor(p, 16, 32);
    p += __shfl_xor(p, 8, 32);
    p += __shfl_xor(p, 4, 32);
    p += __shfl_xor(p, 2, 32);
    p += __shfl_xor(p, 1, 32);
    if ((c & 31) == 0) logit_s[kk][h] = p * 0.17677669529663687f;  // 1/sqrt(32)
  }
  __syncthreads();
  if (c < NH) {
    float mx = -1e30f;
    for (int kk = 0; kk < KNB; kk++) mx = fmaxf(mx, logit_s[kk][c]);
    float w[KNB]; float sum = 0.f;
    for (int kk = 0; kk < KNB; kk++) { w[kk] = expf(logit_s[kk][c] - mx); sum += w[kk]; }
    float inv = 1.f / sum;
    for (int kk = 0; kk < KNB; kk++) attw_s[kk][c] = w[kk] * inv;
  }
  __syncthreads();
  float att = 0.f;
#pragma unroll
  for (int kk = 0; kk < KNB; kk++) att += attw_s[kk][h] * vcs[kk];
  att_s[c] = att;
  __syncthreads();
  int o = c & 127, half = c >> 7;
  float p = 0.f;
  const float* wo = Wo + (size_t)half*128*SDIM + o;
  for (int cc = 0; cc < 128; ++cc) p += att_s[half*128 + cc] * wo[(size_t)cc*SDIM];
  part_s[half][o] = p;
  __syncthreads();
  if (c < 128) x[(size_t)n*SDIM + c] += part_s[0][c] + part_s[1][c] + bo[c];
}

// ---------------- output head (f32 output) ----------------
__global__ __launch_bounds__(128) void head_kernel(const float* __restrict__ enc,
    const float* Ws, const float* bs, const float* Wc, const float* bc,
    const float* Wconc, const float* bconc, const float* Wwt, const float* bwt,
    const float* Wfac, const float* bfac, const float* __restrict__ angles, float* __restrict__ out) {
  int n = blockIdx.x, t = threadIdx.x;
  __shared__ float es[128];
  __shared__ float outs[103];
  es[t] = enc[(size_t)n*SDIM + t];
  __syncthreads();
  const float* W = nullptr; const float* bb = nullptr; int col = 0, nc = 0;
  if (t < 30)       { W = Ws;    bb = bs;    col = t;       nc = 30; }
  else if (t < 60)  { W = Wc;    bb = bc;    col = t - 30;  nc = 30; }
  else if (t < 90)  { W = Wconc; bb = bconc; col = t - 60;  nc = 30; }
  else if (t < 100) { W = Wwt;   bb = bwt;   col = t - 90;  nc = 10; }
  else if (t < 103) { W = Wfac;  bb = bfac;  col = t - 100; nc = 3;  }
  if (W) {
    float acc = bb[col];
    for (int j = 0; j < 128; j++) acc += es[j] * W[j*nc + col];
    outs[t] = acc;
  }
  __syncthreads();
  if (t < MIXN) {
    float mx = -1e30f;
    for (int m = 0; m < MIXN; m++) mx = fmaxf(mx, outs[90 + m]);
    float sum = 0.f;
    for (int m = 0; m < MIXN; m++) sum += expf(outs[90 + m] - mx);
    out[(size_t)n*MIXN + t] = expf(outs[90 + t] - mx) / sum;
  }
  if (t < 30) {
    int j = t / 10;
    float v = atan2f(outs[t], outs[30 + t]);
    float a0 = angles[n*3 + 0], a1 = angles[n*3 + 1];
    if (j == 1) v += outs[100] * a0;
    if (j == 2) v += outs[101] * a0 + outs[102] * a1;
    out[(size_t)NRES*MIXN + (size_t)n*30 + t] = v;
    float z = outs[60 + t];
    float sg = 1.f / (1.f + expf(-z));
    out[(size_t)NRES*MIXN + (size_t)NRES*30 + (size_t)n*30 + t] = 0.1f + 1000.f * sg;
  }
}

// ---------------- launch ----------------
extern "C" void kernel_launch(void* const* d_in, const int* in_sizes, int n_in,
                              void* d_out, int out_size, void* d_ws, size_t ws_size,
                              hipStream_t stream) {
  const float* angles   = (const float*)d_in[0];
  const float* tertiary = (const float*)d_in[1];
  const int*   structure = (const int*)d_in[2];
  // d_in[3] = subgraph (unused)
  const float* W_in  = (const float*)d_in[4];  const float* b_in  = (const float*)d_in[5];
  const float* W_pre = (const float*)d_in[6];  const float* b_pre = (const float*)d_in[7];
  const float* ln1_g = (const float*)d_in[8];  const float* ln1_b = (const float*)d_in[9];
  const float* ln2_g = (const float*)d_in[10]; const float* ln2_b = (const float*)d_in[11];
  const float* Wq = (const float*)d_in[12]; const float* bq = (const float*)d_in[13];
  const float* Wk = (const float*)d_in[14]; const float* bk = (const float*)d_in[15];
  const float* Wv = (const float*)d_in[16]; const float* bv = (const float*)d_in[17];
  const float* Wo = (const float*)d_in[18]; const float* bo = (const float*)d_in[19];
  const float* W1 = (const float*)d_in[20]; const float* b1 = (const float*)d_in[21];
  const float* W2 = (const float*)d_in[22]; const float* b2 = (const float*)d_in[23];
  const float* W3 = (const float*)d_in[24]; const float* b3 = (const float*)d_in[25];
  const float* Ws = (const float*)d_in[26]; const float* bs = (const float*)d_in[27];
  const float* Wc = (const float*)d_in[28]; const float* bc = (const float*)d_in[29];
  const float* Wconc = (const float*)d_in[30]; const float* bconc = (const float*)d_in[31];
  const float* Wwt = (const float*)d_in[32]; const float* bwt = (const float*)d_in[33];
  const float* Wfac = (const float*)d_in[34]; const float* bfac = (const float*)d_in[35];

  // workspace layout (bytes), all f32; total ~54.1 MB (Rounds 1&2 behaved
  // identically at 62.5 vs 28 MiB => ws_size >= 62.5 MB)
  char* wsb = (char*)d_ws;
  float* pos  = (float*)(wsb + 0);           //    98,304 B
  float* Rm   = (float*)(wsb + 98304);       //   294,912 B
  float* edg  = (float*)(wsb + 393216);      // 11,796,480 B
  float* x    = (float*)(wsb + 12189696);    //  4,194,304 B (residual)
  float* nx   = (float*)(wsb + 16384000);    //  4,194,304 B
  float* qb   = (float*)(wsb + 20578304);    //  8,388,608 B
  float* pkb  = (float*)(wsb + 28966912);    //  8,388,608 B
  float* pvb  = (float*)(wsb + 37355520);    //  8,388,608 B + 8,388,608 B spare tail
  float* h1   = qb;                          // 16 MiB over qb+pkb (dead by then)
  float* h2   = pvb;                         // 16 MiB over pvb+tail; ends 54,132,736

  pos_kernel<<<dim3((NRES+255)/256), dim3(256), 0, stream>>>(tertiary, pos);
  frames_kernel<<<dim3((NRES+255)/256), dim3(256), 0, stream>>>(pos, Rm);
  edges_kernel<<<dim3((NRES*KNB+255)/256), dim3(256), 0, stream>>>(pos, Rm, structure, edg);
  init_kernel<<<dim3(NRES), dim3(128), 0, stream>>>(angles, W_in, b_in, W_pre, b_pre, x);

  for (int d = 0; d < 3; ++d) {
    ln_kernel<<<dim3(NRES), dim3(128), 0, stream>>>(x, ln1_g + d*SDIM, ln1_b + d*SDIM, nx);
    // q = nx@Wq + bq ; Pk = nx@Wk[:128] ; Pv = nx@Wv[:128]  (edge part of k/v fused into attention)
    gemm_kernel<0><<<dim3(QDIM/64, NRES/64), dim3(256), 0, stream>>>(
        nx, Wq + (size_t)d*SDIM*QDIM, bq + d*QDIM, qb, NRES, SDIM, QDIM);
    gemm_kernel<0><<<dim3(QDIM/64, NRES/64), dim3(256), 0, stream>>>(
        nx, Wk + (size_t)d*(SDIM+EDIM)*QDIM, nullptr, pkb, NRES, SDIM, QDIM);
    gemm_kernel<0><<<dim3(QDIM/64, NRES/64), dim3(256), 0, stream>>>(
        nx, Wv + (size_t)d*(SDIM+EDIM)*QDIM, nullptr, pvb, NRES, SDIM, QDIM);
    attn_kernel<<<dim3(NRES), dim3(256), 0, stream>>>(qb, pkb, pvb, edg, structure,
        Wk + (size_t)d*(SDIM+EDIM)*QDIM + (size_t)SDIM*QDIM, bk + d*QDIM,
        Wv + (size_t)d*(SDIM+EDIM)*QDIM + (size_t)SDIM*QDIM, bv + d*QDIM,
        Wo + (size_t)d*QDIM*SDIM, bo + d*SDIM, x);
    ln_kernel<<<dim3(NRES), dim3(128), 0, stream>>>(x, ln2_g + d*SDIM, ln2_b + d*SDIM, nx);
    gemm_kernel<1><<<dim3(HIDD/64, NRES/64), dim3(256), 0, stream>>>(
        nx, W1 + (size_t)d*SDIM*HIDD, b1 + d*HIDD, h1, NRES, SDIM, HIDD);
    gemm_kernel<1><<<dim3(HIDD/64, NRES/64), dim3(256), 0, stream>>>(
        h1, W2 + (size_t)d*HIDD*HIDD, b2 + d*HIDD, h2, NRES, HIDD, HIDD);
    gemm_kernel<2><<<dim3(SDIM/64, NRES/64), dim3(256), 0, stream>>>(
        h2, W3 + (size_t)d*HIDD*SDIM, b3 + d*SDIM, x, NRES, HIDD, SDIM);
  }

  head_kernel<<<dim3(NRES), dim3(128), 0, stream>>>(x, Ws, bs, Wc, bc, Wconc, bconc,
      Wwt, bwt, Wfac, bfac, angles, (float*)d_out);
}

// Round 5
// 1062.363 us; speedup vs baseline: 1.5037x; 1.5037x over previous
//
#include <hip/hip_runtime.h>
#include <hip/hip_bf16.h>
#include <stdint.h>

// Problem constants
#define NRES 8192
#define KNB  15
#define SDIM 128
#define EDIM 24
#define HIDD 512
#define NH   8
#define QDIM 256   // H*A
#define MIXN 10

struct F3 { float x, y, z; };
__device__ __forceinline__ F3 f3sub(F3 a, F3 b) { return {a.x-b.x, a.y-b.y, a.z-b.z}; }
__device__ __forceinline__ F3 f3cross(F3 a, F3 b) {
  return {a.y*b.z - a.z*b.y, a.z*b.x - a.x*b.z, a.x*b.y - a.y*b.x};
}
__device__ __forceinline__ F3 f3norm(F3 a) {
  float l = sqrtf(a.x*a.x + a.y*a.y + a.z*a.z) + 1e-8f;
  float r = 1.f / l;
  return {a.x*r, a.y*r, a.z*r};
}
__device__ __forceinline__ F3 ldpos(const float* p, int i) { return {p[i*3], p[i*3+1], p[i*3+2]}; }

// ---------------- geometry ----------------
__global__ void pos_kernel(const float* __restrict__ tert, float* __restrict__ pos) {
  int n = blockIdx.x * blockDim.x + threadIdx.x;
  if (n >= NRES) return;
  pos[n*3+0] = tert[n*9+3];
  pos[n*3+1] = tert[n*9+4];
  pos[n*3+2] = tert[n*9+5];
}

__global__ void frames_kernel(const float* __restrict__ pos, float* __restrict__ R) {
  int m = blockIdx.x * blockDim.x + threadIdx.x;
  if (m >= NRES) return;
  int s = m - 1; if (s < 0) s = 0; if (s > NRES-3) s = NRES-3;
  F3 p0 = ldpos(pos, s), p1 = ldpos(pos, s+1), p2 = ldpos(pos, s+2);
  F3 u0 = f3norm(f3sub(p1, p0));
  F3 u1 = f3norm(f3sub(p2, p1));
  F3 b  = f3norm(f3sub(u0, u1));
  F3 nn = f3norm(f3cross(u0, u1));
  F3 o  = f3cross(b, nn);
  float* r = R + m*9;
  r[0]=b.x; r[1]=nn.x; r[2]=o.x;
  r[3]=b.y; r[4]=nn.y; r[5]=o.y;
  r[6]=b.z; r[7]=nn.z; r[8]=o.z;
}

__device__ __forceinline__ float quat_comp(float t, float a, float b) {
  float s = (a > b) ? 1.f : ((a < b) ? -1.f : 0.f);
  return 0.5f * sqrtf(fmaxf(1e-8f, t)) * s;
}

__global__ void edges_kernel(const float* __restrict__ pos, const float* __restrict__ R,
                             const int* __restrict__ structure, float* __restrict__ edges) {
  int id = blockIdx.x * blockDim.x + threadIdx.x;
  if (id >= NRES*KNB) return;
  int n = id / KNB;
  int tprev = (n - 1) & (NRES - 1);
  int sidx = structure[id];
  F3 pt = ldpos(pos, tprev), ps = ldpos(pos, sidx);
  F3 dv = f3sub(ps, pt);
  float dist = sqrtf(dv.x*dv.x + dv.y*dv.y + dv.z*dv.z);
  float rinv = 1.f / (dist + 1e-8f);
  F3 dh = {dv.x*rinv, dv.y*rinv, dv.z*rinv};
  float Rt[9], Rs[9];
#pragma unroll
  for (int i = 0; i < 9; i++) { Rt[i] = R[tprev*9+i]; Rs[i] = R[sidx*9+i]; }
  float dir[3];
#pragma unroll
  for (int i = 0; i < 3; i++) dir[i] = Rt[i]*dh.x + Rt[3+i]*dh.y + Rt[6+i]*dh.z;
  float Rr[9];
#pragma unroll
  for (int i = 0; i < 3; i++)
#pragma unroll
    for (int l = 0; l < 3; l++)
      Rr[i*3+l] = Rt[i]*Rs[l] + Rt[3+i]*Rs[3+l] + Rt[6+i]*Rs[6+l];
  float m00 = Rr[0], m11 = Rr[4], m22 = Rr[8];
  float qw = 0.5f * sqrtf(fmaxf(1e-8f, 1.f + m00 + m11 + m22));
  float qx = quat_comp(1.f + m00 - m11 - m22, Rr[7], Rr[5]);
  float qy = quat_comp(1.f - m00 + m11 - m22, Rr[2], Rr[6]);
  float qz = quat_comp(1.f - m00 - m11 + m22, Rr[3], Rr[1]);
  float* e = edges + (size_t)id * EDIM;
#pragma unroll
  for (int j = 0; j < 16; j++) {
    float mu = (20.f / 15.f) * j;            // linspace(0,20,16)
    float zz = (dist - mu) * (1.f / 1.25f);  // sigma = 20/16
    e[j] = expf(-zz*zz);
  }
  e[16] = dir[0]; e[17] = dir[1]; e[18] = dir[2];
  e[19] = qw; e[20] = qx; e[21] = qy; e[22] = qz;
  e[23] = (float)(sidx - tprev) * 0.01f;
}

// ---------------- input embedding ----------------
__global__ __launch_bounds__(128) void init_kernel(const float* __restrict__ angles,
    const float* __restrict__ W_in, const float* __restrict__ b_in,
    const float* __restrict__ W_pre, const float* __restrict__ b_pre, float* __restrict__ x) {
  int n = blockIdx.x, c = threadIdx.x;
  __shared__ float fs[128];
  float af[6];
  if (n == 0) { af[0]=af[1]=af[2]=0.f; af[3]=af[4]=af[5]=1.f; }
  else {
#pragma unroll
    for (int j = 0; j < 3; j++) {
      float p = angles[(n-1)*3 + j];
      af[j] = sinf(p); af[3+j] = cosf(p);
    }
  }
  float f = b_in[c];
#pragma unroll
  for (int j = 0; j < 6; j++) f += af[j] * W_in[j*SDIM + c];
  fs[c] = f;
  __syncthreads();
  float xv = b_pre[c];
  for (int j = 0; j < 128; j++) xv += fs[j] * W_pre[j*SDIM + c];
  x[(size_t)n*SDIM + c] = xv;
}

// ---------------- layernorm: f32 -> f32 ----------------
__global__ __launch_bounds__(128) void ln_kernel(const float* __restrict__ x,
    const float* __restrict__ g, const float* __restrict__ b, float* __restrict__ out) {
  int n = blockIdx.x, c = threadIdx.x;
  float v = x[(size_t)n*SDIM + c];
  float s = v;
#pragma unroll
  for (int m = 32; m >= 1; m >>= 1) s += __shfl_xor(s, m, 64);
  __shared__ float p1[2], p2[2];
  if ((c & 63) == 0) p1[c >> 6] = s;
  __syncthreads();
  float mean = (p1[0] + p1[1]) * (1.f/128.f);
  float d = v - mean;
  float s2 = d * d;
#pragma unroll
  for (int m = 32; m >= 1; m >>= 1) s2 += __shfl_xor(s2, m, 64);
  if ((c & 63) == 0) p2[c >> 6] = s2;
  __syncthreads();
  float var = (p2[0] + p2[1]) * (1.f/128.f);
  out[(size_t)n*SDIM + c] = d * rsqrtf(var + 1e-5f) * g[c] + b[c];
}

// ---------------- tiled SGEMM: C(MxN) = A(MxK,f32) @ B(KxN,f32), f32 acc ----------------
// MODE 0: C = AB + bias ; MODE 1: C = relu(AB + bias) ; MODE 2: C += AB + bias
// Requires M%64==0, N%64==0, K%16==0.
template<int MODE>
__global__ __launch_bounds__(256) void gemm_kernel(const float* __restrict__ A, const float* __restrict__ B,
    const float* __restrict__ bias, float* __restrict__ C, int M, int Kd, int Nd) {
  __shared__ float As[16][68];
  __shared__ float Bs[16][68];
  int t = threadIdx.x;
  int m0 = blockIdx.y * 64, n0 = blockIdx.x * 64;
  int tx = t & 15, ty = t >> 4;
  int am = t >> 2, ak = (t & 3) * 4;   // A stage: 64 rows x 16 k, 4 f32 each
  int bk = t >> 4, bn = (t & 15) * 4;  // B stage: 16 k x 64 cols, 4 f32 each
  float acc[4][4] = {};
  for (int k0 = 0; k0 < Kd; k0 += 16) {
    float4 araw = *(const float4*)(A + (size_t)(m0 + am)*Kd + k0 + ak);
    float4 braw = *(const float4*)(B + (size_t)(k0 + bk)*Nd + n0 + bn);
    __syncthreads();
    As[ak+0][am] = araw.x; As[ak+1][am] = araw.y; As[ak+2][am] = araw.z; As[ak+3][am] = araw.w;
    Bs[bk][bn+0] = braw.x; Bs[bk][bn+1] = braw.y; Bs[bk][bn+2] = braw.z; Bs[bk][bn+3] = braw.w;
    __syncthreads();
#pragma unroll
    for (int k = 0; k < 16; ++k) {
      float4 a = *(const float4*)&As[k][ty*4];
      float4 b = *(const float4*)&Bs[k][tx*4];
      acc[0][0] += a.x*b.x; acc[0][1] += a.x*b.y; acc[0][2] += a.x*b.z; acc[0][3] += a.x*b.w;
      acc[1][0] += a.y*b.x; acc[1][1] += a.y*b.y; acc[1][2] += a.y*b.z; acc[1][3] += a.y*b.w;
      acc[2][0] += a.z*b.x; acc[2][1] += a.z*b.y; acc[2][2] += a.z*b.z; acc[2][3] += a.z*b.w;
      acc[3][0] += a.w*b.x; acc[3][1] += a.w*b.y; acc[3][2] += a.w*b.z; acc[3][3] += a.w*b.w;
    }
  }
  int mb = m0 + ty*4, nb = n0 + tx*4;
  float bj[4];
#pragma unroll
  for (int j = 0; j < 4; j++) bj[j] = bias ? bias[nb + j] : 0.f;
#pragma unroll
  for (int i = 0; i < 4; i++) {
    float* crow = C + (size_t)(mb + i)*Nd + nb;
#pragma unroll
    for (int j = 0; j < 4; j++) {
      float v = acc[i][j] + bj[j];
      if (MODE == 1) v = fmaxf(v, 0.f);
      if (MODE == 2) crow[j] += v; else crow[j] = v;
    }
  }
}

// ---------------- qW precompute: qW[n,h,j] = sum_{c in head h} q[n,c]*WkB[j][c]; j==24 -> bk ----------------
__global__ __launch_bounds__(256) void qw_kernel(const float* __restrict__ q,
    const float* __restrict__ WkB, const float* __restrict__ bk, float* __restrict__ qW) {
  int n = blockIdx.x, t = threadIdx.x;
  if (t >= NH*25) return;
  int h = t / 25, jj = t % 25;
  const float* qr = q + (size_t)n*QDIM + h*32;
  const float* wr = (jj < 24) ? (WkB + (size_t)jj*QDIM + h*32) : (bk + h*32);
  float acc = 0.f;
#pragma unroll
  for (int c2 = 0; c2 < 32; c2++) acc += qr[c2] * wr[c2];
  qW[(size_t)n*(NH*25) + t] = acc;
}

// ---------------- fused attention (one block = one node, 256 threads = 256 channels) ----------------
// logits: q.(pk[s]) gather-dot + edge terms via precomputed qW; softmax;
// att[c] = sum_kk attw*pv[s][c] + bv[c] + sum_j ew[h][j]*WvB[j][c]  (ew = attw @ e)
// Output projection att@Wo handled by gemm_kernel<2> afterwards.
__global__ __launch_bounds__(256) void attn_kernel(const float* __restrict__ q,
    const float* __restrict__ pk, const float* __restrict__ pv,
    const float* __restrict__ edges, const int* __restrict__ structure,
    const float* __restrict__ qW, const float* __restrict__ WvB,
    const float* __restrict__ bv, float* __restrict__ att) {
  int n = blockIdx.x, c = threadIdx.x;
  __shared__ float e_s[KNB*EDIM];       // 360
  __shared__ int   si[KNB];
  __shared__ float qw_s[NH*25];         // 200
  __shared__ float logit_s[KNB][NH];    // 120
  __shared__ float attw_s[KNB][NH];     // 120
  __shared__ float ew_s[NH][EDIM];      // 192
  __shared__ float wv_s[EDIM*QDIM];     // 6144 floats = 24 KB

  for (int i = c; i < KNB*EDIM; i += 256) e_s[i] = edges[(size_t)n*KNB*EDIM + i];
  for (int i = c; i < NH*25;    i += 256) qw_s[i] = qW[(size_t)n*(NH*25) + i];
  for (int i = c; i < EDIM*QDIM; i += 256) wv_s[i] = WvB[i];
  if (c < KNB) si[c] = structure[n*KNB + c];
  float qc = q[(size_t)n*QDIM + c];
  float bvc = bv[c];
  __syncthreads();

  int s[KNB];
#pragma unroll
  for (int kk = 0; kk < KNB; kk++) s[kk] = si[kk];
  int h = c >> 5;

  // gather-dot part of logits
#pragma unroll
  for (int kk = 0; kk < KNB; kk++) {
    float p = qc * pk[(size_t)s[kk]*QDIM + c];
    p += __shfl_xor(p, 16, 32);
    p += __shfl_xor(p, 8, 32);
    p += __shfl_xor(p, 4, 32);
    p += __shfl_xor(p, 2, 32);
    p += __shfl_xor(p, 1, 32);
    if ((c & 31) == 0) logit_s[kk][h] = p;
  }
  __syncthreads();
  // add edge + bias terms, scale
  if (c < KNB*NH) {
    int kk = c / NH, hh = c % NH;
    float l = logit_s[kk][hh] + qw_s[hh*25 + 24];
    const float* qwr = &qw_s[hh*25];
    const float* er  = &e_s[kk*EDIM];
#pragma unroll
    for (int j = 0; j < EDIM; j++) l += qwr[j] * er[j];
    logit_s[kk][hh] = l * 0.17677669529663687f;  // 1/sqrt(32)
  }
  __syncthreads();
  if (c < NH) {
    float mx = -1e30f;
    for (int kk = 0; kk < KNB; kk++) mx = fmaxf(mx, logit_s[kk][c]);
    float w[KNB]; float sum = 0.f;
    for (int kk = 0; kk < KNB; kk++) { w[kk] = expf(logit_s[kk][c] - mx); sum += w[kk]; }
    float inv = 1.f / sum;
    for (int kk = 0; kk < KNB; kk++) attw_s[kk][c] = w[kk] * inv;
  }
  __syncthreads();
  // ew = attw @ e  (per head)
  if (c < NH*EDIM) {
    int hh = c / EDIM, j = c % EDIM;
    float acc = 0.f;
#pragma unroll
    for (int kk = 0; kk < KNB; kk++) acc += attw_s[kk][hh] * e_s[kk*EDIM + j];
    ew_s[hh][j] = acc;
  }
  // gathered V part (all threads)
  float vg = bvc;
#pragma unroll
  for (int kk = 0; kk < KNB; kk++) vg += attw_s[kk][h] * pv[(size_t)s[kk]*QDIM + c];
  __syncthreads();
  float o = vg;
#pragma unroll
  for (int j = 0; j < EDIM; j++) o += ew_s[h][j] * wv_s[j*QDIM + c];
  att[(size_t)n*QDIM + c] = o;
}

// ---------------- output head (f32 output) ----------------
__global__ __launch_bounds__(128) void head_kernel(const float* __restrict__ enc,
    const float* Ws, const float* bs, const float* Wc, const float* bc,
    const float* Wconc, const float* bconc, const float* Wwt, const float* bwt,
    const float* Wfac, const float* bfac, const float* __restrict__ angles, float* __restrict__ out) {
  int n = blockIdx.x, t = threadIdx.x;
  __shared__ float es[128];
  __shared__ float outs[103];
  es[t] = enc[(size_t)n*SDIM + t];
  __syncthreads();
  const float* W = nullptr; const float* bb = nullptr; int col = 0, nc = 0;
  if (t < 30)       { W = Ws;    bb = bs;    col = t;       nc = 30; }
  else if (t < 60)  { W = Wc;    bb = bc;    col = t - 30;  nc = 30; }
  else if (t < 90)  { W = Wconc; bb = bconc; col = t - 60;  nc = 30; }
  else if (t < 100) { W = Wwt;   bb = bwt;   col = t - 90;  nc = 10; }
  else if (t < 103) { W = Wfac;  bb = bfac;  col = t - 100; nc = 3;  }
  if (W) {
    float acc = bb[col];
    for (int j = 0; j < 128; j++) acc += es[j] * W[j*nc + col];
    outs[t] = acc;
  }
  __syncthreads();
  if (t < MIXN) {
    float mx = -1e30f;
    for (int m = 0; m < MIXN; m++) mx = fmaxf(mx, outs[90 + m]);
    float sum = 0.f;
    for (int m = 0; m < MIXN; m++) sum += expf(outs[90 + m] - mx);
    out[(size_t)n*MIXN + t] = expf(outs[90 + t] - mx) / sum;
  }
  if (t < 30) {
    int j = t / 10;
    float v = atan2f(outs[t], outs[30 + t]);
    float a0 = angles[n*3 + 0], a1 = angles[n*3 + 1];
    if (j == 1) v += outs[100] * a0;
    if (j == 2) v += outs[101] * a0 + outs[102] * a1;
    out[(size_t)NRES*MIXN + (size_t)n*30 + t] = v;
    float z = outs[60 + t];
    float sg = 1.f / (1.f + expf(-z));
    out[(size_t)NRES*MIXN + (size_t)NRES*30 + (size_t)n*30 + t] = 0.1f + 1000.f * sg;
  }
}

// ---------------- launch ----------------
extern "C" void kernel_launch(void* const* d_in, const int* in_sizes, int n_in,
                              void* d_out, int out_size, void* d_ws, size_t ws_size,
                              hipStream_t stream) {
  const float* angles   = (const float*)d_in[0];
  const float* tertiary = (const float*)d_in[1];
  const int*   structure = (const int*)d_in[2];
  // d_in[3] = subgraph (unused)
  const float* W_in  = (const float*)d_in[4];  const float* b_in  = (const float*)d_in[5];
  const float* W_pre = (const float*)d_in[6];  const float* b_pre = (const float*)d_in[7];
  const float* ln1_g = (const float*)d_in[8];  const float* ln1_b = (const float*)d_in[9];
  const float* ln2_g = (const float*)d_in[10]; const float* ln2_b = (const float*)d_in[11];
  const float* Wq = (const float*)d_in[12]; const float* bq = (const float*)d_in[13];
  const float* Wk = (const float*)d_in[14]; const float* bk = (const float*)d_in[15];
  const float* Wv = (const float*)d_in[16]; const float* bv = (const float*)d_in[17];
  const float* Wo = (const float*)d_in[18]; const float* bo = (const float*)d_in[19];
  const float* W1 = (const float*)d_in[20]; const float* b1 = (const float*)d_in[21];
  const float* W2 = (const float*)d_in[22]; const float* b2 = (const float*)d_in[23];
  const float* W3 = (const float*)d_in[24]; const float* b3 = (const float*)d_in[25];
  const float* Ws = (const float*)d_in[26]; const float* bs = (const float*)d_in[27];
  const float* Wc = (const float*)d_in[28]; const float* bc = (const float*)d_in[29];
  const float* Wconc = (const float*)d_in[30]; const float* bconc = (const float*)d_in[31];
  const float* Wwt = (const float*)d_in[32]; const float* bwt = (const float*)d_in[33];
  const float* Wfac = (const float*)d_in[34]; const float* bfac = (const float*)d_in[35];

  // workspace layout (bytes); high-water ~62.5 MB (Round-1 footprint ran fine)
  char* wsb = (char*)d_ws;
  float* pos  = (float*)(wsb + 0);           //    98,304 B
  float* Rm   = (float*)(wsb + 98304);       //   294,912 B
  float* edg  = (float*)(wsb + 393216);      // 11,796,480 B
  float* x    = (float*)(wsb + 12189696);    //  4,194,304 B (residual)
  float* nx   = (float*)(wsb + 16384000);    //  4,194,304 B
  float* qb   = (float*)(wsb + 20578304);    //  8,388,608 B
  float* pkb  = (float*)(wsb + 28966912);    //  8,388,608 B
  float* pvb  = (float*)(wsb + 37355520);    //  8,388,608 B
  float* qWb  = (float*)(wsb + 45744128);    //  6,553,600 B (8192*200 f32)
  float* attb = (float*)(wsb + 52297728);    //  8,388,608 B (8192*256 f32)
  float* h1   = qb;                          // 16 MiB over qb+pkb (dead by then)
  float* h2   = pvb;                         // 16 MiB over pvb+qWb+attb head (dead); ends 62,521,344

  pos_kernel<<<dim3((NRES+255)/256), dim3(256), 0, stream>>>(tertiary, pos);
  frames_kernel<<<dim3((NRES+255)/256), dim3(256), 0, stream>>>(pos, Rm);
  edges_kernel<<<dim3((NRES*KNB+255)/256), dim3(256), 0, stream>>>(pos, Rm, structure, edg);
  init_kernel<<<dim3(NRES), dim3(128), 0, stream>>>(angles, W_in, b_in, W_pre, b_pre, x);

  for (int d = 0; d < 3; ++d) {
    const float* WkD = Wk + (size_t)d*(SDIM+EDIM)*QDIM;
    const float* WvD = Wv + (size_t)d*(SDIM+EDIM)*QDIM;
    ln_kernel<<<dim3(NRES), dim3(128), 0, stream>>>(x, ln1_g + d*SDIM, ln1_b + d*SDIM, nx);
    // q = nx@Wq + bq ; Pk = nx@Wk[:128] ; Pv = nx@Wv[:128]  (edge part of k/v folded algebraically)
    gemm_kernel<0><<<dim3(QDIM/64, NRES/64), dim3(256), 0, stream>>>(
        nx, Wq + (size_t)d*SDIM*QDIM, bq + d*QDIM, qb, NRES, SDIM, QDIM);
    gemm_kernel<0><<<dim3(QDIM/64, NRES/64), dim3(256), 0, stream>>>(
        nx, WkD, nullptr, pkb, NRES, SDIM, QDIM);
    gemm_kernel<0><<<dim3(QDIM/64, NRES/64), dim3(256), 0, stream>>>(
        nx, WvD, nullptr, pvb, NRES, SDIM, QDIM);
    qw_kernel<<<dim3(NRES), dim3(256), 0, stream>>>(
        qb, WkD + (size_t)SDIM*QDIM, bk + d*QDIM, qWb);
    attn_kernel<<<dim3(NRES), dim3(256), 0, stream>>>(qb, pkb, pvb, edg, structure,
        qWb, WvD + (size_t)SDIM*QDIM, bv + d*QDIM, attb);
    gemm_kernel<2><<<dim3(SDIM/64, NRES/64), dim3(256), 0, stream>>>(
        attb, Wo + (size_t)d*QDIM*SDIM, bo + d*SDIM, x, NRES, QDIM, SDIM);
    ln_kernel<<<dim3(NRES), dim3(128), 0, stream>>>(x, ln2_g + d*SDIM, ln2_b + d*SDIM, nx);
    gemm_kernel<1><<<dim3(HIDD/64, NRES/64), dim3(256), 0, stream>>>(
        nx, W1 + (size_t)d*SDIM*HIDD, b1 + d*HIDD, h1, NRES, SDIM, HIDD);
    gemm_kernel<1><<<dim3(HIDD/64, NRES/64), dim3(256), 0, stream>>>(
        h1, W2 + (size_t)d*HIDD*HIDD, b2 + d*HIDD, h2, NRES, HIDD, HIDD);
    gemm_kernel<2><<<dim3(SDIM/64, NRES/64), dim3(256), 0, stream>>>(
        h2, W3 + (size_t)d*HIDD*SDIM, b3 + d*SDIM, x, NRES, HIDD, SDIM);
  }

  head_kernel<<<dim3(NRES), dim3(128), 0, stream>>>(x, Ws, bs, Wc, bc, Wconc, bconc,
      Wwt, bwt, Wfac, bfac, angles, (float*)d_out);
}

// Round 6
// 994.907 us; speedup vs baseline: 1.6057x; 1.0678x over previous
//
#include <hip/hip_runtime.h>
#include <hip/hip_bf16.h>
#include <stdint.h>

// Problem constants
#define NRES 8192
#define KNB  15
#define SDIM 128
#define EDIM 24
#define HIDD 512
#define NH   8
#define QDIM 256   // H*A
#define MIXN 10

struct F3 { float x, y, z; };
__device__ __forceinline__ F3 f3sub(F3 a, F3 b) { return {a.x-b.x, a.y-b.y, a.z-b.z}; }
__device__ __forceinline__ F3 f3cross(F3 a, F3 b) {
  return {a.y*b.z - a.z*b.y, a.z*b.x - a.x*b.z, a.x*b.y - a.y*b.x};
}
__device__ __forceinline__ F3 f3norm(F3 a) {
  float l = sqrtf(a.x*a.x + a.y*a.y + a.z*a.z) + 1e-8f;
  float r = 1.f / l;
  return {a.x*r, a.y*r, a.z*r};
}
__device__ __forceinline__ F3 ldpos(const float* p, int i) { return {p[i*3], p[i*3+1], p[i*3+2]}; }

// ---------------- geometry ----------------
__global__ void pos_kernel(const float* __restrict__ tert, float* __restrict__ pos) {
  int n = blockIdx.x * blockDim.x + threadIdx.x;
  if (n >= NRES) return;
  pos[n*3+0] = tert[n*9+3];
  pos[n*3+1] = tert[n*9+4];
  pos[n*3+2] = tert[n*9+5];
}

__global__ void frames_kernel(const float* __restrict__ pos, float* __restrict__ R) {
  int m = blockIdx.x * blockDim.x + threadIdx.x;
  if (m >= NRES) return;
  int s = m - 1; if (s < 0) s = 0; if (s > NRES-3) s = NRES-3;
  F3 p0 = ldpos(pos, s), p1 = ldpos(pos, s+1), p2 = ldpos(pos, s+2);
  F3 u0 = f3norm(f3sub(p1, p0));
  F3 u1 = f3norm(f3sub(p2, p1));
  F3 b  = f3norm(f3sub(u0, u1));
  F3 nn = f3norm(f3cross(u0, u1));
  F3 o  = f3cross(b, nn);
  float* r = R + m*9;
  r[0]=b.x; r[1]=nn.x; r[2]=o.x;
  r[3]=b.y; r[4]=nn.y; r[5]=o.y;
  r[6]=b.z; r[7]=nn.z; r[8]=o.z;
}

__device__ __forceinline__ float quat_comp(float t, float a, float b) {
  float s = (a > b) ? 1.f : ((a < b) ? -1.f : 0.f);
  return 0.5f * sqrtf(fmaxf(1e-8f, t)) * s;
}

__global__ void edges_kernel(const float* __restrict__ pos, const float* __restrict__ R,
                             const int* __restrict__ structure, float* __restrict__ edges) {
  int id = blockIdx.x * blockDim.x + threadIdx.x;
  if (id >= NRES*KNB) return;
  int n = id / KNB;
  int tprev = (n - 1) & (NRES - 1);
  int sidx = structure[id];
  F3 pt = ldpos(pos, tprev), ps = ldpos(pos, sidx);
  F3 dv = f3sub(ps, pt);
  float dist = sqrtf(dv.x*dv.x + dv.y*dv.y + dv.z*dv.z);
  float rinv = 1.f / (dist + 1e-8f);
  F3 dh = {dv.x*rinv, dv.y*rinv, dv.z*rinv};
  float Rt[9], Rs[9];
#pragma unroll
  for (int i = 0; i < 9; i++) { Rt[i] = R[tprev*9+i]; Rs[i] = R[sidx*9+i]; }
  float dir[3];
#pragma unroll
  for (int i = 0; i < 3; i++) dir[i] = Rt[i]*dh.x + Rt[3+i]*dh.y + Rt[6+i]*dh.z;
  float Rr[9];
#pragma unroll
  for (int i = 0; i < 3; i++)
#pragma unroll
    for (int l = 0; l < 3; l++)
      Rr[i*3+l] = Rt[i]*Rs[l] + Rt[3+i]*Rs[3+l] + Rt[6+i]*Rs[6+l];
  float m00 = Rr[0], m11 = Rr[4], m22 = Rr[8];
  float qw = 0.5f * sqrtf(fmaxf(1e-8f, 1.f + m00 + m11 + m22));
  float qx = quat_comp(1.f + m00 - m11 - m22, Rr[7], Rr[5]);
  float qy = quat_comp(1.f - m00 + m11 - m22, Rr[2], Rr[6]);
  float qz = quat_comp(1.f - m00 - m11 + m22, Rr[3], Rr[1]);
  float* e = edges + (size_t)id * EDIM;
#pragma unroll
  for (int j = 0; j < 16; j++) {
    float mu = (20.f / 15.f) * j;            // linspace(0,20,16)
    float zz = (dist - mu) * (1.f / 1.25f);  // sigma = 20/16
    e[j] = expf(-zz*zz);
  }
  e[16] = dir[0]; e[17] = dir[1]; e[18] = dir[2];
  e[19] = qw; e[20] = qx; e[21] = qy; e[22] = qz;
  e[23] = (float)(sidx - tprev) * 0.01f;
}

// ---------------- input embedding ----------------
__global__ __launch_bounds__(128) void init_kernel(const float* __restrict__ angles,
    const float* __restrict__ W_in, const float* __restrict__ b_in,
    const float* __restrict__ W_pre, const float* __restrict__ b_pre, float* __restrict__ x) {
  int n = blockIdx.x, c = threadIdx.x;
  __shared__ float fs[128];
  float af[6];
  if (n == 0) { af[0]=af[1]=af[2]=0.f; af[3]=af[4]=af[5]=1.f; }
  else {
#pragma unroll
    for (int j = 0; j < 3; j++) {
      float p = angles[(n-1)*3 + j];
      af[j] = sinf(p); af[3+j] = cosf(p);
    }
  }
  float f = b_in[c];
#pragma unroll
  for (int j = 0; j < 6; j++) f += af[j] * W_in[j*SDIM + c];
  fs[c] = f;
  __syncthreads();
  float xv = b_pre[c];
  for (int j = 0; j < 128; j++) xv += fs[j] * W_pre[j*SDIM + c];
  x[(size_t)n*SDIM + c] = xv;
}

// ---------------- layernorm: f32 -> f32 ----------------
__global__ __launch_bounds__(128) void ln_kernel(const float* __restrict__ x,
    const float* __restrict__ g, const float* __restrict__ b, float* __restrict__ out) {
  int n = blockIdx.x, c = threadIdx.x;
  float v = x[(size_t)n*SDIM + c];
  float s = v;
#pragma unroll
  for (int m = 32; m >= 1; m >>= 1) s += __shfl_xor(s, m, 64);
  __shared__ float p1[2], p2[2];
  if ((c & 63) == 0) p1[c >> 6] = s;
  __syncthreads();
  float mean = (p1[0] + p1[1]) * (1.f/128.f);
  float d = v - mean;
  float s2 = d * d;
#pragma unroll
  for (int m = 32; m >= 1; m >>= 1) s2 += __shfl_xor(s2, m, 64);
  if ((c & 63) == 0) p2[c >> 6] = s2;
  __syncthreads();
  float var = (p2[0] + p2[1]) * (1.f/128.f);
  out[(size_t)n*SDIM + c] = d * rsqrtf(var + 1e-5f) * g[c] + b[c];
}

// ---------------- tiled SGEMM 64x64: for N==128/256 shapes ----------------
// MODE 0: C = AB + bias ; MODE 1: C = relu(AB + bias) ; MODE 2: C += AB + bias
template<int MODE>
__global__ __launch_bounds__(256) void gemm_kernel(const float* __restrict__ A, const float* __restrict__ B,
    const float* __restrict__ bias, float* __restrict__ C, int M, int Kd, int Nd) {
  __shared__ float As[16][68];
  __shared__ float Bs[16][68];
  int t = threadIdx.x;
  int m0 = blockIdx.y * 64, n0 = blockIdx.x * 64;
  int tx = t & 15, ty = t >> 4;
  int am = t >> 2, ak = (t & 3) * 4;
  int bk = t >> 4, bn = (t & 15) * 4;
  float acc[4][4] = {};
  for (int k0 = 0; k0 < Kd; k0 += 16) {
    float4 araw = *(const float4*)(A + (size_t)(m0 + am)*Kd + k0 + ak);
    float4 braw = *(const float4*)(B + (size_t)(k0 + bk)*Nd + n0 + bn);
    __syncthreads();
    As[ak+0][am] = araw.x; As[ak+1][am] = araw.y; As[ak+2][am] = araw.z; As[ak+3][am] = araw.w;
    Bs[bk][bn+0] = braw.x; Bs[bk][bn+1] = braw.y; Bs[bk][bn+2] = braw.z; Bs[bk][bn+3] = braw.w;
    __syncthreads();
#pragma unroll
    for (int k = 0; k < 16; ++k) {
      float4 a = *(const float4*)&As[k][ty*4];
      float4 b = *(const float4*)&Bs[k][tx*4];
      acc[0][0] += a.x*b.x; acc[0][1] += a.x*b.y; acc[0][2] += a.x*b.z; acc[0][3] += a.x*b.w;
      acc[1][0] += a.y*b.x; acc[1][1] += a.y*b.y; acc[1][2] += a.y*b.z; acc[1][3] += a.y*b.w;
      acc[2][0] += a.z*b.x; acc[2][1] += a.z*b.y; acc[2][2] += a.z*b.z; acc[2][3] += a.z*b.w;
      acc[3][0] += a.w*b.x; acc[3][1] += a.w*b.y; acc[3][2] += a.w*b.z; acc[3][3] += a.w*b.w;
    }
  }
  int mb = m0 + ty*4, nb = n0 + tx*4;
  float bj[4];
#pragma unroll
  for (int j = 0; j < 4; j++) bj[j] = bias ? bias[nb + j] : 0.f;
#pragma unroll
  for (int i = 0; i < 4; i++) {
    float* crow = C + (size_t)(mb + i)*Nd + nb;
#pragma unroll
    for (int j = 0; j < 4; j++) {
      float v = acc[i][j] + bj[j];
      if (MODE == 1) v = fmaxf(v, 0.f);
      if (MODE == 2) crow[j] += v; else crow[j] = v;
    }
  }
}

// ---------------- tiled SGEMM 128x128, 8x8 micro-tile: for N>=512 shapes ----------------
// 64 FMA per 4 ds_read_b128 -> VALU-bound. M%128==0, N%128==0, K%16==0.
template<int MODE>
__global__ __launch_bounds__(256) void gemm128_kernel(const float* __restrict__ A, const float* __restrict__ B,
    const float* __restrict__ bias, float* __restrict__ C, int M, int Kd, int Nd) {
  __shared__ float As[16][132];
  __shared__ float Bs[16][136];
  int t = threadIdx.x;
  int m0 = blockIdx.y * 128, n0 = blockIdx.x * 128;
  int tx = t & 15, ty = t >> 4;        // 16x16 thread grid, 8x8 each
  int am = t >> 1, ak = (t & 1) * 8;   // A stage: 128 rows x 16 k, 8 f32 each
  int bk = t >> 4, bn = (t & 15) * 8;  // B stage: 16 k x 128 cols, 8 f32 each
  float acc[8][8] = {};
  for (int k0 = 0; k0 < Kd; k0 += 16) {
    const float* ap = A + (size_t)(m0 + am)*Kd + k0 + ak;
    float4 a0 = *(const float4*)(ap);
    float4 a1 = *(const float4*)(ap + 4);
    const float* bp = B + (size_t)(k0 + bk)*Nd + n0 + bn;
    float4 b0 = *(const float4*)(bp);
    float4 b1 = *(const float4*)(bp + 4);
    __syncthreads();
    As[ak+0][am]=a0.x; As[ak+1][am]=a0.y; As[ak+2][am]=a0.z; As[ak+3][am]=a0.w;
    As[ak+4][am]=a1.x; As[ak+5][am]=a1.y; As[ak+6][am]=a1.z; As[ak+7][am]=a1.w;
    *(float4*)&Bs[bk][bn] = b0; *(float4*)&Bs[bk][bn+4] = b1;
    __syncthreads();
#pragma unroll
    for (int k = 0; k < 16; ++k) {
      float a[8], b[8];
      *(float4*)(a)   = *(const float4*)&As[k][ty*8];
      *(float4*)(a+4) = *(const float4*)&As[k][ty*8+4];
      *(float4*)(b)   = *(const float4*)&Bs[k][tx*8];
      *(float4*)(b+4) = *(const float4*)&Bs[k][tx*8+4];
#pragma unroll
      for (int i = 0; i < 8; i++)
#pragma unroll
        for (int j = 0; j < 8; j++) acc[i][j] += a[i]*b[j];
    }
  }
  int mb = m0 + ty*8, nb = n0 + tx*8;
  float bj[8];
#pragma unroll
  for (int j = 0; j < 8; j++) bj[j] = bias ? bias[nb + j] : 0.f;
#pragma unroll
  for (int i = 0; i < 8; i++) {
    float* crow = C + (size_t)(mb + i)*Nd + nb;
#pragma unroll
    for (int j = 0; j < 8; j++) {
      float v = acc[i][j] + bj[j];
      if (MODE == 1) v = fmaxf(v, 0.f);
      if (MODE == 2) crow[j] += v; else crow[j] = v;
    }
  }
}

// ---------------- qW precompute: qW[n,h,j] = sum_{c in head h} q[n,c]*WkB[j][c]; j==24 -> bk ----------------
__global__ __launch_bounds__(256) void qw_kernel(const float* __restrict__ q,
    const float* __restrict__ WkB, const float* __restrict__ bk, float* __restrict__ qW) {
  int n = blockIdx.x, t = threadIdx.x;
  if (t >= NH*25) return;
  int h = t / 25, jj = t % 25;
  const float* qr = q + (size_t)n*QDIM + h*32;
  const float* wr = (jj < 24) ? (WkB + (size_t)jj*QDIM + h*32) : (bk + h*32);
  float acc = 0.f;
#pragma unroll
  for (int c2 = 0; c2 < 32; c2++) acc += qr[c2] * wr[c2];
  qW[(size_t)n*(NH*25) + t] = acc;
}

// ---------------- fused attention (one block = one node, 256 threads = 256 channels) ----------------
// Gathers issued immediately (indices via per-thread L1-broadcast loads, no barrier);
// V-gather held in regs through softmax. WvB read direct from global (L2-hot).
__global__ __launch_bounds__(256) void attn_kernel(const float* __restrict__ q,
    const float* __restrict__ pk, const float* __restrict__ pv,
    const float* __restrict__ edges, const int* __restrict__ structure,
    const float* __restrict__ qW, const float* __restrict__ WvB,
    const float* __restrict__ bv, float* __restrict__ att) {
  int n = blockIdx.x, c = threadIdx.x;
  __shared__ float e_s[KNB*EDIM];       // 360
  __shared__ float qw_s[NH*25];         // 200
  __shared__ float logit_s[KNB][NH];    // 120
  __shared__ float attw_s[KNB][NH];     // 120
  __shared__ float ew_s[NH][EDIM];      // 192

  // indices: same address across threads -> L1 broadcast; no barrier needed
  int s[KNB];
#pragma unroll
  for (int kk = 0; kk < KNB; kk++) s[kk] = structure[n*KNB + kk];
  // issue all 30 gathers immediately
  float pks[KNB], pvs[KNB];
#pragma unroll
  for (int kk = 0; kk < KNB; kk++) pks[kk] = pk[(size_t)s[kk]*QDIM + c];
#pragma unroll
  for (int kk = 0; kk < KNB; kk++) pvs[kk] = pv[(size_t)s[kk]*QDIM + c];
  float qc = q[(size_t)n*QDIM + c];
  float bvc = bv[c];
  // stage edges + qW while gathers are in flight
  for (int i = c; i < KNB*EDIM; i += 256) e_s[i] = edges[(size_t)n*KNB*EDIM + i];
  for (int i = c; i < NH*25;    i += 256) qw_s[i] = qW[(size_t)n*(NH*25) + i];

  int h = c >> 5;
  // gather-dot part of logits
#pragma unroll
  for (int kk = 0; kk < KNB; kk++) {
    float p = qc * pks[kk];
    p += __shfl_xor(p, 16, 32);
    p += __shfl_xor(p, 8, 32);
    p += __shfl_xor(p, 4, 32);
    p += __shfl_xor(p, 2, 32);
    p += __shfl_xor(p, 1, 32);
    if ((c & 31) == 0) logit_s[kk][h] = p;
  }
  __syncthreads();
  // add edge + bias terms, scale
  if (c < KNB*NH) {
    int kk = c / NH, hh = c % NH;
    float l = logit_s[kk][hh] + qw_s[hh*25 + 24];
    const float* qwr = &qw_s[hh*25];
    const float* er  = &e_s[kk*EDIM];
#pragma unroll
    for (int j = 0; j < EDIM; j++) l += qwr[j] * er[j];
    logit_s[kk][hh] = l * 0.17677669529663687f;  // 1/sqrt(32)
  }
  __syncthreads();
  if (c < NH) {
    float mx = -1e30f;
    for (int kk = 0; kk < KNB; kk++) mx = fmaxf(mx, logit_s[kk][c]);
    float w[KNB]; float sum = 0.f;
    for (int kk = 0; kk < KNB; kk++) { w[kk] = expf(logit_s[kk][c] - mx); sum += w[kk]; }
    float inv = 1.f / sum;
    for (int kk = 0; kk < KNB; kk++) attw_s[kk][c] = w[kk] * inv;
  }
  __syncthreads();
  // ew = attw @ e  (per head)
  if (c < NH*EDIM) {
    int hh = c / EDIM, j = c % EDIM;
    float acc = 0.f;
#pragma unroll
    for (int kk = 0; kk < KNB; kk++) acc += attw_s[kk][hh] * e_s[kk*EDIM + j];
    ew_s[hh][j] = acc;
  }
  __syncthreads();
  // gathered V part from regs + edge-V term
  float vg = bvc;
#pragma unroll
  for (int kk = 0; kk < KNB; kk++) vg += attw_s[kk][h] * pvs[kk];
  float o = vg;
#pragma unroll
  for (int j = 0; j < EDIM; j++) o += ew_s[h][j] * WvB[(size_t)j*QDIM + c];
  att[(size_t)n*QDIM + c] = o;
}

// ---------------- output head (f32 output) ----------------
__global__ __launch_bounds__(128) void head_kernel(const float* __restrict__ enc,
    const float* Ws, const float* bs, const float* Wc, const float* bc,
    const float* Wconc, const float* bconc, const float* Wwt, const float* bwt,
    const float* Wfac, const float* bfac, const float* __restrict__ angles, float* __restrict__ out) {
  int n = blockIdx.x, t = threadIdx.x;
  __shared__ float es[128];
  __shared__ float outs[103];
  es[t] = enc[(size_t)n*SDIM + t];
  __syncthreads();
  const float* W = nullptr; const float* bb = nullptr; int col = 0, nc = 0;
  if (t < 30)       { W = Ws;    bb = bs;    col = t;       nc = 30; }
  else if (t < 60)  { W = Wc;    bb = bc;    col = t - 30;  nc = 30; }
  else if (t < 90)  { W = Wconc; bb = bconc; col = t - 60;  nc = 30; }
  else if (t < 100) { W = Wwt;   bb = bwt;   col = t - 90;  nc = 10; }
  else if (t < 103) { W = Wfac;  bb = bfac;  col = t - 100; nc = 3;  }
  if (W) {
    float acc = bb[col];
    for (int j = 0; j < 128; j++) acc += es[j] * W[j*nc + col];
    outs[t] = acc;
  }
  __syncthreads();
  if (t < MIXN) {
    float mx = -1e30f;
    for (int m = 0; m < MIXN; m++) mx = fmaxf(mx, outs[90 + m]);
    float sum = 0.f;
    for (int m = 0; m < MIXN; m++) sum += expf(outs[90 + m] - mx);
    out[(size_t)n*MIXN + t] = expf(outs[90 + t] - mx) / sum;
  }
  if (t < 30) {
    int j = t / 10;
    float v = atan2f(outs[t], outs[30 + t]);
    float a0 = angles[n*3 + 0], a1 = angles[n*3 + 1];
    if (j == 1) v += outs[100] * a0;
    if (j == 2) v += outs[101] * a0 + outs[102] * a1;
    out[(size_t)NRES*MIXN + (size_t)n*30 + t] = v;
    float z = outs[60 + t];
    float sg = 1.f / (1.f + expf(-z));
    out[(size_t)NRES*MIXN + (size_t)NRES*30 + (size_t)n*30 + t] = 0.1f + 1000.f * sg;
  }
}

// ---------------- launch ----------------
extern "C" void kernel_launch(void* const* d_in, const int* in_sizes, int n_in,
                              void* d_out, int out_size, void* d_ws, size_t ws_size,
                              hipStream_t stream) {
  const float* angles   = (const float*)d_in[0];
  const float* tertiary = (const float*)d_in[1];
  const int*   structure = (const int*)d_in[2];
  // d_in[3] = subgraph (unused)
  const float* W_in  = (const float*)d_in[4];  const float* b_in  = (const float*)d_in[5];
  const float* W_pre = (const float*)d_in[6];  const float* b_pre = (const float*)d_in[7];
  const float* ln1_g = (const float*)d_in[8];  const float* ln1_b = (const float*)d_in[9];
  const float* ln2_g = (const float*)d_in[10]; const float* ln2_b = (const float*)d_in[11];
  const float* Wq = (const float*)d_in[12]; const float* bq = (const float*)d_in[13];
  const float* Wk = (const float*)d_in[14]; const float* bk = (const float*)d_in[15];
  const float* Wv = (const float*)d_in[16]; const float* bv = (const float*)d_in[17];
  const float* Wo = (const float*)d_in[18]; const float* bo = (const float*)d_in[19];
  const float* W1 = (const float*)d_in[20]; const float* b1 = (const float*)d_in[21];
  const float* W2 = (const float*)d_in[22]; const float* b2 = (const float*)d_in[23];
  const float* W3 = (const float*)d_in[24]; const float* b3 = (const float*)d_in[25];
  const float* Ws = (const float*)d_in[26]; const float* bs = (const float*)d_in[27];
  const float* Wc = (const float*)d_in[28]; const float* bc = (const float*)d_in[29];
  const float* Wconc = (const float*)d_in[30]; const float* bconc = (const float*)d_in[31];
  const float* Wwt = (const float*)d_in[32]; const float* bwt = (const float*)d_in[33];
  const float* Wfac = (const float*)d_in[34]; const float* bfac = (const float*)d_in[35];

  // workspace layout (bytes); high-water ~62.5 MB (Round-1 footprint ran fine)
  char* wsb = (char*)d_ws;
  float* pos  = (float*)(wsb + 0);           //    98,304 B
  float* Rm   = (float*)(wsb + 98304);       //   294,912 B
  float* edg  = (float*)(wsb + 393216);      // 11,796,480 B
  float* x    = (float*)(wsb + 12189696);    //  4,194,304 B (residual)
  float* nx   = (float*)(wsb + 16384000);    //  4,194,304 B
  float* qb   = (float*)(wsb + 20578304);    //  8,388,608 B
  float* pkb  = (float*)(wsb + 28966912);    //  8,388,608 B
  float* pvb  = (float*)(wsb + 37355520);    //  8,388,608 B
  float* qWb  = (float*)(wsb + 45744128);    //  6,553,600 B (8192*200 f32)
  float* attb = (float*)(wsb + 52297728);    //  8,388,608 B (8192*256 f32)
  float* h1   = qb;                          // 16 MiB over qb+pkb (dead by then)
  float* h2   = pvb;                         // 16 MiB over pvb+qWb (dead); ends 62,521,344

  pos_kernel<<<dim3((NRES+255)/256), dim3(256), 0, stream>>>(tertiary, pos);
  frames_kernel<<<dim3((NRES+255)/256), dim3(256), 0, stream>>>(pos, Rm);
  edges_kernel<<<dim3((NRES*KNB+255)/256), dim3(256), 0, stream>>>(pos, Rm, structure, edg);
  init_kernel<<<dim3(NRES), dim3(128), 0, stream>>>(angles, W_in, b_in, W_pre, b_pre, x);

  for (int d = 0; d < 3; ++d) {
    const float* WkD = Wk + (size_t)d*(SDIM+EDIM)*QDIM;
    const float* WvD = Wv + (size_t)d*(SDIM+EDIM)*QDIM;
    ln_kernel<<<dim3(NRES), dim3(128), 0, stream>>>(x, ln1_g + d*SDIM, ln1_b + d*SDIM, nx);
    // q = nx@Wq + bq ; Pk = nx@Wk[:128] ; Pv = nx@Wv[:128]  (edge part of k/v folded algebraically)
    gemm_kernel<0><<<dim3(QDIM/64, NRES/64), dim3(256), 0, stream>>>(
        nx, Wq + (size_t)d*SDIM*QDIM, bq + d*QDIM, qb, NRES, SDIM, QDIM);
    gemm_kernel<0><<<dim3(QDIM/64, NRES/64), dim3(256), 0, stream>>>(
        nx, WkD, nullptr, pkb, NRES, SDIM, QDIM);
    gemm_kernel<0><<<dim3(QDIM/64, NRES/64), dim3(256), 0, stream>>>(
        nx, WvD, nullptr, pvb, NRES, SDIM, QDIM);
    qw_kernel<<<dim3(NRES), dim3(256), 0, stream>>>(
        qb, WkD + (size_t)SDIM*QDIM, bk + d*QDIM, qWb);
    attn_kernel<<<dim3(NRES), dim3(256), 0, stream>>>(qb, pkb, pvb, edg, structure,
        qWb, WvD + (size_t)SDIM*QDIM, bv + d*QDIM, attb);
    gemm_kernel<2><<<dim3(SDIM/64, NRES/64), dim3(256), 0, stream>>>(
        attb, Wo + (size_t)d*QDIM*SDIM, bo + d*SDIM, x, NRES, QDIM, SDIM);
    ln_kernel<<<dim3(NRES), dim3(128), 0, stream>>>(x, ln2_g + d*SDIM, ln2_b + d*SDIM, nx);
    gemm128_kernel<1><<<dim3(HIDD/128, NRES/128), dim3(256), 0, stream>>>(
        nx, W1 + (size_t)d*SDIM*HIDD, b1 + d*HIDD, h1, NRES, SDIM, HIDD);
    gemm128_kernel<1><<<dim3(HIDD/128, NRES/128), dim3(256), 0, stream>>>(
        h1, W2 + (size_t)d*HIDD*HIDD, b2 + d*HIDD, h2, NRES, HIDD, HIDD);
    gemm_kernel<2><<<dim3(SDIM/64, NRES/64), dim3(256), 0, stream>>>(
        h2, W3 + (size_t)d*HIDD*SDIM, b3 + d*SDIM, x, NRES, HIDD, SDIM);
  }

  head_kernel<<<dim3(NRES), dim3(128), 0, stream>>>(x, Ws, bs, Wc, bc, Wconc, bconc,
      Wwt, bwt, Wfac, bfac, angles, (float*)d_out);
}

// Round 7
// 676.514 us; speedup vs baseline: 2.3614x; 1.4706x over previous
//
#include <hip/hip_runtime.h>
#include <hip/hip_bf16.h>
#include <stdint.h>

// Problem constants
#define NRES 8192
#define KNB  15
#define SDIM 128
#define EDIM 24
#define HIDD 512
#define NH   8
#define QDIM 256   // H*A
#define MIXN 10

typedef _Float16 f16;
typedef _Float16 f16x8 __attribute__((ext_vector_type(8)));
typedef float f32x4 __attribute__((ext_vector_type(4)));

struct F3 { float x, y, z; };
__device__ __forceinline__ F3 f3sub(F3 a, F3 b) { return {a.x-b.x, a.y-b.y, a.z-b.z}; }
__device__ __forceinline__ F3 f3cross(F3 a, F3 b) {
  return {a.y*b.z - a.z*b.y, a.z*b.x - a.x*b.z, a.x*b.y - a.y*b.x};
}
__device__ __forceinline__ F3 f3norm(F3 a) {
  float l = sqrtf(a.x*a.x + a.y*a.y + a.z*a.z) + 1e-8f;
  float r = 1.f / l;
  return {a.x*r, a.y*r, a.z*r};
}
__device__ __forceinline__ F3 ldpos(const float* p, int i) { return {p[i*3], p[i*3+1], p[i*3+2]}; }

// ---------------- geometry ----------------
__global__ void pos_kernel(const float* __restrict__ tert, float* __restrict__ pos) {
  int n = blockIdx.x * blockDim.x + threadIdx.x;
  if (n >= NRES) return;
  pos[n*3+0] = tert[n*9+3];
  pos[n*3+1] = tert[n*9+4];
  pos[n*3+2] = tert[n*9+5];
}

__global__ void frames_kernel(const float* __restrict__ pos, float* __restrict__ R) {
  int m = blockIdx.x * blockDim.x + threadIdx.x;
  if (m >= NRES) return;
  int s = m - 1; if (s < 0) s = 0; if (s > NRES-3) s = NRES-3;
  F3 p0 = ldpos(pos, s), p1 = ldpos(pos, s+1), p2 = ldpos(pos, s+2);
  F3 u0 = f3norm(f3sub(p1, p0));
  F3 u1 = f3norm(f3sub(p2, p1));
  F3 b  = f3norm(f3sub(u0, u1));
  F3 nn = f3norm(f3cross(u0, u1));
  F3 o  = f3cross(b, nn);
  float* r = R + m*9;
  r[0]=b.x; r[1]=nn.x; r[2]=o.x;
  r[3]=b.y; r[4]=nn.y; r[5]=o.y;
  r[6]=b.z; r[7]=nn.z; r[8]=o.z;
}

__device__ __forceinline__ float quat_comp(float t, float a, float b) {
  float s = (a > b) ? 1.f : ((a < b) ? -1.f : 0.f);
  return 0.5f * sqrtf(fmaxf(1e-8f, t)) * s;
}

__global__ void edges_kernel(const float* __restrict__ pos, const float* __restrict__ R,
                             const int* __restrict__ structure, float* __restrict__ edges) {
  int id = blockIdx.x * blockDim.x + threadIdx.x;
  if (id >= NRES*KNB) return;
  int n = id / KNB;
  int tprev = (n - 1) & (NRES - 1);
  int sidx = structure[id];
  F3 pt = ldpos(pos, tprev), ps = ldpos(pos, sidx);
  F3 dv = f3sub(ps, pt);
  float dist = sqrtf(dv.x*dv.x + dv.y*dv.y + dv.z*dv.z);
  float rinv = 1.f / (dist + 1e-8f);
  F3 dh = {dv.x*rinv, dv.y*rinv, dv.z*rinv};
  float Rt[9], Rs[9];
#pragma unroll
  for (int i = 0; i < 9; i++) { Rt[i] = R[tprev*9+i]; Rs[i] = R[sidx*9+i]; }
  float dir[3];
#pragma unroll
  for (int i = 0; i < 3; i++) dir[i] = Rt[i]*dh.x + Rt[3+i]*dh.y + Rt[6+i]*dh.z;
  float Rr[9];
#pragma unroll
  for (int i = 0; i < 3; i++)
#pragma unroll
    for (int l = 0; l < 3; l++)
      Rr[i*3+l] = Rt[i]*Rs[l] + Rt[3+i]*Rs[3+l] + Rt[6+i]*Rs[6+l];
  float m00 = Rr[0], m11 = Rr[4], m22 = Rr[8];
  float qw = 0.5f * sqrtf(fmaxf(1e-8f, 1.f + m00 + m11 + m22));
  float qx = quat_comp(1.f + m00 - m11 - m22, Rr[7], Rr[5]);
  float qy = quat_comp(1.f - m00 + m11 - m22, Rr[2], Rr[6]);
  float qz = quat_comp(1.f - m00 - m11 + m22, Rr[3], Rr[1]);
  float* e = edges + (size_t)id * EDIM;
#pragma unroll
  for (int j = 0; j < 16; j++) {
    float mu = (20.f / 15.f) * j;            // linspace(0,20,16)
    float zz = (dist - mu) * (1.f / 1.25f);  // sigma = 20/16
    e[j] = expf(-zz*zz);
  }
  e[16] = dir[0]; e[17] = dir[1]; e[18] = dir[2];
  e[19] = qw; e[20] = qx; e[21] = qy; e[22] = qz;
  e[23] = (float)(sidx - tprev) * 0.01f;
}

// ---------------- input embedding ----------------
__global__ __launch_bounds__(128) void init_kernel(const float* __restrict__ angles,
    const float* __restrict__ W_in, const float* __restrict__ b_in,
    const float* __restrict__ W_pre, const float* __restrict__ b_pre, float* __restrict__ x) {
  int n = blockIdx.x, c = threadIdx.x;
  __shared__ float fs[128];
  float af[6];
  if (n == 0) { af[0]=af[1]=af[2]=0.f; af[3]=af[4]=af[5]=1.f; }
  else {
#pragma unroll
    for (int j = 0; j < 3; j++) {
      float p = angles[(n-1)*3 + j];
      af[j] = sinf(p); af[3+j] = cosf(p);
    }
  }
  float f = b_in[c];
#pragma unroll
  for (int j = 0; j < 6; j++) f += af[j] * W_in[j*SDIM + c];
  fs[c] = f;
  __syncthreads();
  float xv = b_pre[c];
  for (int j = 0; j < 128; j++) xv += fs[j] * W_pre[j*SDIM + c];
  x[(size_t)n*SDIM + c] = xv;
}

// ---------------- layernorm: f32 in -> fp16 out (GEMM A-operand) ----------------
__global__ __launch_bounds__(128) void ln_kernel(const float* __restrict__ x,
    const float* __restrict__ g, const float* __restrict__ b, f16* __restrict__ out) {
  int n = blockIdx.x, c = threadIdx.x;
  float v = x[(size_t)n*SDIM + c];
  float s = v;
#pragma unroll
  for (int m = 32; m >= 1; m >>= 1) s += __shfl_xor(s, m, 64);
  __shared__ float p1[2], p2[2];
  if ((c & 63) == 0) p1[c >> 6] = s;
  __syncthreads();
  float mean = (p1[0] + p1[1]) * (1.f/128.f);
  float d = v - mean;
  float s2 = d * d;
#pragma unroll
  for (int m = 32; m >= 1; m >>= 1) s2 += __shfl_xor(s2, m, 64);
  if ((c & 63) == 0) p2[c >> 6] = s2;
  __syncthreads();
  float var = (p2[0] + p2[1]) * (1.f/128.f);
  out[(size_t)n*SDIM + c] = (f16)(d * rsqrtf(var + 1e-5f) * g[c] + b[c]);
}

// ---------------- weight convert+swizzle: f32 [K][N] -> fp16 frag layout ----------------
// dst[((k>>3)*dstN + colOff + n)*8 + (k&7)] so a b-frag (fixed n, 8 consecutive k) is one 16B load.
__global__ void convswz_kernel(const float* __restrict__ src, int srcLayerStride, int srcLd,
    int K, int N, f16* __restrict__ dst, int dstLayerHalves, int dstN, int colOff) {
  int d = blockIdx.y;
  const float* s = src + (size_t)d * srcLayerStride;
  f16* o = dst + (size_t)d * dstLayerHalves;
  for (int i = blockIdx.x*blockDim.x + threadIdx.x; i < K*N; i += gridDim.x*blockDim.x) {
    int k = i / N, n = i - k*N;
    o[((size_t)(k>>3)*dstN + colOff + n)*8 + (k&7)] = (f16)s[(size_t)k*srcLd + n];
  }
}

__global__ void bias768_kernel(const float* __restrict__ bq, float* __restrict__ out) {
  int i = blockIdx.x*blockDim.x + threadIdx.x;
  if (i >= 3*768) return;
  int d = i / 768, col = i - d*768;
  out[i] = (col < 256) ? bq[d*QDIM + col] : 0.f;  // pk/pv biases folded into attn algebra
}

// ---------------- MFMA GEMM: C(8192xN) = A(8192xK fp16) @ Bsw(KxN fp16 swizzled) ----------------
// One wave = 32(M) x 64(N) tile, no LDS, no syncthreads. M fixed at 8192 (mTiles=256).
// MODE 1: fp16 C = relu(AB+bias) ; MODE 2: f32 C += AB+bias ; MODE 3: f32 qkv-split store (Nd=768)
template<int MODE>
__global__ __launch_bounds__(256) void gemm_mfma(const f16* __restrict__ A,
    const f16* __restrict__ Bsw, const float* __restrict__ bias,
    void* __restrict__ Cv, int Kd, int Nd) {
  int w = blockIdx.x * 4 + (threadIdx.x >> 6);
  int lane = threadIdx.x & 63;
  int wm = w & 255, wn = w >> 8;       // mTiles = 8192/32 = 256; wm fastest for B reuse on-CU
  int m0 = wm * 32, n0 = wn * 64;
  int r16 = lane & 15, qd = lane >> 4;
  f32x4 acc[2][4] = {};
  const f16* aBase = A + (size_t)(m0 + r16)*Kd + qd*8;
  for (int kc = 0; kc < Kd; kc += 32) {
    f16x8 af0 = *(const f16x8*)(aBase + kc);
    f16x8 af1 = *(const f16x8*)(aBase + (size_t)16*Kd + kc);
    const f16* bBase = Bsw + ((size_t)((kc>>3) + qd)*Nd + n0 + r16)*8;
    f16x8 bf[4];
#pragma unroll
    for (int nt = 0; nt < 4; nt++) bf[nt] = *(const f16x8*)(bBase + nt*16*8);
#pragma unroll
    for (int nt = 0; nt < 4; nt++) {
      acc[0][nt] = __builtin_amdgcn_mfma_f32_16x16x32_f16(af0, bf[nt], acc[0][nt], 0, 0, 0);
      acc[1][nt] = __builtin_amdgcn_mfma_f32_16x16x32_f16(af1, bf[nt], acc[1][nt], 0, 0, 0);
    }
  }
  // D layout: row = qd*4 + r, col = r16 (per 16x16 tile)
#pragma unroll
  for (int mt = 0; mt < 2; mt++) {
#pragma unroll
    for (int nt = 0; nt < 4; nt++) {
      int col = n0 + nt*16 + r16;
      float bj = bias ? bias[col] : 0.f;
#pragma unroll
      for (int r = 0; r < 4; r++) {
        int row = m0 + mt*16 + qd*4 + r;
        float v = acc[mt][nt][r] + bj;
        if (MODE == 1) {
          ((f16*)Cv)[(size_t)row*Nd + col] = (f16)fmaxf(v, 0.f);
        } else if (MODE == 2) {
          ((float*)Cv)[(size_t)row*Nd + col] += v;
        } else {  // MODE 3: cols [0,256)->q, [256,512)->pk, [512,768)->pv, each stride 256
          int third = col >> 8, cl = col & 255;
          ((float*)Cv)[(size_t)third*NRES*QDIM + (size_t)row*QDIM + cl] = v;
        }
      }
    }
  }
}

// ---------------- qW precompute: qW[n,h,j] = sum_{c in head h} q[n,c]*WkB[j][c]; j==24 -> bk ----------------
__global__ __launch_bounds__(256) void qw_kernel(const float* __restrict__ q,
    const float* __restrict__ WkB, const float* __restrict__ bk, float* __restrict__ qW) {
  int n = blockIdx.x, t = threadIdx.x;
  if (t >= NH*25) return;
  int h = t / 25, jj = t % 25;
  const float* qr = q + (size_t)n*QDIM + h*32;
  const float* wr = (jj < 24) ? (WkB + (size_t)jj*QDIM + h*32) : (bk + h*32);
  float acc = 0.f;
#pragma unroll
  for (int c2 = 0; c2 < 32; c2++) acc += qr[c2] * wr[c2];
  qW[(size_t)n*(NH*25) + t] = acc;
}

// ---------------- fused attention (one block = one node, 256 threads = 256 channels) ----------------
__global__ __launch_bounds__(256) void attn_kernel(const float* __restrict__ q,
    const float* __restrict__ pk, const float* __restrict__ pv,
    const float* __restrict__ edges, const int* __restrict__ structure,
    const float* __restrict__ qW, const float* __restrict__ WvB,
    const float* __restrict__ bv, f16* __restrict__ att) {
  int n = blockIdx.x, c = threadIdx.x;
  __shared__ float e_s[KNB*EDIM];
  __shared__ float qw_s[NH*25];
  __shared__ float logit_s[KNB][NH];
  __shared__ float attw_s[KNB][NH];
  __shared__ float ew_s[NH][EDIM];

  int s[KNB];
#pragma unroll
  for (int kk = 0; kk < KNB; kk++) s[kk] = structure[n*KNB + kk];
  float pks[KNB], pvs[KNB];
#pragma unroll
  for (int kk = 0; kk < KNB; kk++) pks[kk] = pk[(size_t)s[kk]*QDIM + c];
#pragma unroll
  for (int kk = 0; kk < KNB; kk++) pvs[kk] = pv[(size_t)s[kk]*QDIM + c];
  float qc = q[(size_t)n*QDIM + c];
  float bvc = bv[c];
  for (int i = c; i < KNB*EDIM; i += 256) e_s[i] = edges[(size_t)n*KNB*EDIM + i];
  for (int i = c; i < NH*25;    i += 256) qw_s[i] = qW[(size_t)n*(NH*25) + i];

  int h = c >> 5;
#pragma unroll
  for (int kk = 0; kk < KNB; kk++) {
    float p = qc * pks[kk];
    p += __shfl_xor(p, 16, 32);
    p += __shfl_xor(p, 8, 32);
    p += __shfl_xor(p, 4, 32);
    p += __shfl_xor(p, 2, 32);
    p += __shfl_xor(p, 1, 32);
    if ((c & 31) == 0) logit_s[kk][h] = p;
  }
  __syncthreads();
  if (c < KNB*NH) {
    int kk = c / NH, hh = c % NH;
    float l = logit_s[kk][hh] + qw_s[hh*25 + 24];
    const float* qwr = &qw_s[hh*25];
    const float* er  = &e_s[kk*EDIM];
#pragma unroll
    for (int j = 0; j < EDIM; j++) l += qwr[j] * er[j];
    logit_s[kk][hh] = l * 0.17677669529663687f;  // 1/sqrt(32)
  }
  __syncthreads();
  if (c < NH) {
    float mx = -1e30f;
    for (int kk = 0; kk < KNB; kk++) mx = fmaxf(mx, logit_s[kk][c]);
    float w[KNB]; float sum = 0.f;
    for (int kk = 0; kk < KNB; kk++) { w[kk] = expf(logit_s[kk][c] - mx); sum += w[kk]; }
    float inv = 1.f / sum;
    for (int kk = 0; kk < KNB; kk++) attw_s[kk][c] = w[kk] * inv;
  }
  __syncthreads();
  if (c < NH*EDIM) {
    int hh = c / EDIM, j = c % EDIM;
    float acc = 0.f;
#pragma unroll
    for (int kk = 0; kk < KNB; kk++) acc += attw_s[kk][hh] * e_s[kk*EDIM + j];
    ew_s[hh][j] = acc;
  }
  __syncthreads();
  float vg = bvc;
#pragma unroll
  for (int kk = 0; kk < KNB; kk++) vg += attw_s[kk][h] * pvs[kk];
  float o = vg;
#pragma unroll
  for (int j = 0; j < EDIM; j++) o += ew_s[h][j] * WvB[(size_t)j*QDIM + c];
  att[(size_t)n*QDIM + c] = (f16)o;
}

// ---------------- output head (f32 output) ----------------
__global__ __launch_bounds__(128) void head_kernel(const float* __restrict__ enc,
    const float* Ws, const float* bs, const float* Wc, const float* bc,
    const float* Wconc, const float* bconc, const float* Wwt, const float* bwt,
    const float* Wfac, const float* bfac, const float* __restrict__ angles, float* __restrict__ out) {
  int n = blockIdx.x, t = threadIdx.x;
  __shared__ float es[128];
  __shared__ float outs[103];
  es[t] = enc[(size_t)n*SDIM + t];
  __syncthreads();
  const float* W = nullptr; const float* bb = nullptr; int col = 0, nc = 0;
  if (t < 30)       { W = Ws;    bb = bs;    col = t;       nc = 30; }
  else if (t < 60)  { W = Wc;    bb = bc;    col = t - 30;  nc = 30; }
  else if (t < 90)  { W = Wconc; bb = bconc; col = t - 60;  nc = 30; }
  else if (t < 100) { W = Wwt;   bb = bwt;   col = t - 90;  nc = 10; }
  else if (t < 103) { W = Wfac;  bb = bfac;  col = t - 100; nc = 3;  }
  if (W) {
    float acc = bb[col];
    for (int j = 0; j < 128; j++) acc += es[j] * W[j*nc + col];
    outs[t] = acc;
  }
  __syncthreads();
  if (t < MIXN) {
    float mx = -1e30f;
    for (int m = 0; m < MIXN; m++) mx = fmaxf(mx, outs[90 + m]);
    float sum = 0.f;
    for (int m = 0; m < MIXN; m++) sum += expf(outs[90 + m] - mx);
    out[(size_t)n*MIXN + t] = expf(outs[90 + t] - mx) / sum;
  }
  if (t < 30) {
    int j = t / 10;
    float v = atan2f(outs[t], outs[30 + t]);
    float a0 = angles[n*3 + 0], a1 = angles[n*3 + 1];
    if (j == 1) v += outs[100] * a0;
    if (j == 2) v += outs[101] * a0 + outs[102] * a1;
    out[(size_t)NRES*MIXN + (size_t)n*30 + t] = v;
    float z = outs[60 + t];
    float sg = 1.f / (1.f + expf(-z));
    out[(size_t)NRES*MIXN + (size_t)NRES*30 + (size_t)n*30 + t] = 0.1f + 1000.f * sg;
  }
}

// ---------------- launch ----------------
extern "C" void kernel_launch(void* const* d_in, const int* in_sizes, int n_in,
                              void* d_out, int out_size, void* d_ws, size_t ws_size,
                              hipStream_t stream) {
  const float* angles   = (const float*)d_in[0];
  const float* tertiary = (const float*)d_in[1];
  const int*   structure = (const int*)d_in[2];
  // d_in[3] = subgraph (unused)
  const float* W_in  = (const float*)d_in[4];  const float* b_in  = (const float*)d_in[5];
  const float* W_pre = (const float*)d_in[6];  const float* b_pre = (const float*)d_in[7];
  const float* ln1_g = (const float*)d_in[8];  const float* ln1_b = (const float*)d_in[9];
  const float* ln2_g = (const float*)d_in[10]; const float* ln2_b = (const float*)d_in[11];
  const float* Wq = (const float*)d_in[12]; const float* bq = (const float*)d_in[13];
  const float* Wk = (const float*)d_in[14]; const float* bk = (const float*)d_in[15];
  const float* Wv = (const float*)d_in[16]; const float* bv = (const float*)d_in[17];
  const float* Wo = (const float*)d_in[18]; const float* bo = (const float*)d_in[19];
  const float* W1 = (const float*)d_in[20]; const float* b1 = (const float*)d_in[21];
  const float* W2 = (const float*)d_in[22]; const float* b2 = (const float*)d_in[23];
  const float* W3 = (const float*)d_in[24]; const float* b3 = (const float*)d_in[25];
  const float* Ws = (const float*)d_in[26]; const float* bs = (const float*)d_in[27];
  const float* Wc = (const float*)d_in[28]; const float* bc = (const float*)d_in[29];
  const float* Wconc = (const float*)d_in[30]; const float* bconc = (const float*)d_in[31];
  const float* Wwt = (const float*)d_in[32]; const float* bwt = (const float*)d_in[33];
  const float* Wfac = (const float*)d_in[34]; const float* bfac = (const float*)d_in[35];

  // workspace layout (bytes); high-water ~57.6 MB (<= 62.5 MB established safe)
  char* wsb = (char*)d_ws;
  float* pos   = (float*)(wsb + 0);
  float* Rm    = (float*)(wsb + 98304);
  float* edg   = (float*)(wsb + 393216);      // 11,796,480 B
  float* x     = (float*)(wsb + 12189696);    //  4 MiB f32 residual
  f16*   nx_h  = (f16*)  (wsb + 16384000);    //  2 MiB fp16 LN output
  float* qWb   = (float*)(wsb + 18481152);    //  6,553,600 B
  f16*   att_h = (f16*)  (wsb + 25034752);    //  4 MiB fp16
  float* qb    = (float*)(wsb + 29229056);    //  8 MiB  (q | pk | pv contiguous)
  float* pkb   = (float*)(wsb + 37617664);    //  8 MiB
  float* pvb   = (float*)(wsb + 46006272);    //  8 MiB -> ends 54,394,880
  f16*   h1h   = (f16*)  (wsb + 29229056);    //  8 MiB alias over qb (dead by FFN)
  f16*   h2h   = (f16*)  (wsb + 37617664);    //  8 MiB alias over pkb
  f16*   qkvw  = (f16*)  (wsb + 54394880);    //  589,824 B (3 x 128x768)
  f16*   w1w   = (f16*)  (wsb + 54984704);    //  393,216 B
  f16*   w2w   = (f16*)  (wsb + 55377920);    //  1,572,864 B
  f16*   w3w   = (f16*)  (wsb + 56950784);    //  393,216 B
  f16*   wow   = (f16*)  (wsb + 57344000);    //  196,608 B
  float* b768  = (float*)(wsb + 57540608);    //  9,216 B -> ends 57,549,824

  pos_kernel<<<dim3((NRES+255)/256), dim3(256), 0, stream>>>(tertiary, pos);
  frames_kernel<<<dim3((NRES+255)/256), dim3(256), 0, stream>>>(pos, Rm);
  edges_kernel<<<dim3((NRES*KNB+255)/256), dim3(256), 0, stream>>>(pos, Rm, structure, edg);
  init_kernel<<<dim3(NRES), dim3(128), 0, stream>>>(angles, W_in, b_in, W_pre, b_pre, x);

  // one-time weight conversions to fp16 frag-swizzled layouts (all 3 layers each)
  convswz_kernel<<<dim3(64,3), 256, 0, stream>>>(Wq, SDIM*QDIM, QDIM, 128, 256, qkvw, 98304, 768, 0);
  convswz_kernel<<<dim3(64,3), 256, 0, stream>>>(Wk, (SDIM+EDIM)*QDIM, QDIM, 128, 256, qkvw, 98304, 768, 256);
  convswz_kernel<<<dim3(64,3), 256, 0, stream>>>(Wv, (SDIM+EDIM)*QDIM, QDIM, 128, 256, qkvw, 98304, 768, 512);
  convswz_kernel<<<dim3(64,3), 256, 0, stream>>>(W1, SDIM*HIDD, HIDD, 128, 512, w1w, 65536, 512, 0);
  convswz_kernel<<<dim3(64,3), 256, 0, stream>>>(W2, HIDD*HIDD, HIDD, 512, 512, w2w, 262144, 512, 0);
  convswz_kernel<<<dim3(64,3), 256, 0, stream>>>(W3, HIDD*SDIM, SDIM, 512, 128, w3w, 65536, 128, 0);
  convswz_kernel<<<dim3(64,3), 256, 0, stream>>>(Wo, QDIM*SDIM, SDIM, 256, 128, wow, 32768, 128, 0);
  bias768_kernel<<<9, 256, 0, stream>>>(bq, b768);

  for (int d = 0; d < 3; ++d) {
    const float* WkD = Wk + (size_t)d*(SDIM+EDIM)*QDIM;
    const float* WvD = Wv + (size_t)d*(SDIM+EDIM)*QDIM;
    ln_kernel<<<dim3(NRES), dim3(128), 0, stream>>>(x, ln1_g + d*SDIM, ln1_b + d*SDIM, nx_h);
    // fused q|pk|pv GEMM: Nd=768 -> split store into qb/pkb/pvb (bias only on q part)
    gemm_mfma<3><<<768, 256, 0, stream>>>(nx_h, qkvw + (size_t)d*98304, b768 + d*768, qb, 128, 768);
    qw_kernel<<<dim3(NRES), dim3(256), 0, stream>>>(
        qb, WkD + (size_t)SDIM*QDIM, bk + d*QDIM, qWb);
    attn_kernel<<<dim3(NRES), dim3(256), 0, stream>>>(qb, pkb, pvb, edg, structure,
        qWb, WvD + (size_t)SDIM*QDIM, bv + d*QDIM, att_h);
    gemm_mfma<2><<<128, 256, 0, stream>>>(att_h, wow + (size_t)d*32768, bo + d*SDIM, x, 256, 128);
    ln_kernel<<<dim3(NRES), dim3(128), 0, stream>>>(x, ln2_g + d*SDIM, ln2_b + d*SDIM, nx_h);
    gemm_mfma<1><<<512, 256, 0, stream>>>(nx_h, w1w + (size_t)d*65536, b1 + d*HIDD, h1h, 128, 512);
    gemm_mfma<1><<<512, 256, 0, stream>>>(h1h, w2w + (size_t)d*262144, b2 + d*HIDD, h2h, 512, 512);
    gemm_mfma<2><<<128, 256, 0, stream>>>(h2h, w3w + (size_t)d*65536, b3 + d*SDIM, x, 512, 128);
  }

  head_kernel<<<dim3(NRES), dim3(128), 0, stream>>>(x, Ws, bs, Wc, bc, Wconc, bconc,
      Wwt, bwt, Wfac, bfac, angles, (float*)d_out);
}